// Round 8
// baseline (170.866 us; speedup 1.0000x reference)
//
#include <hip/hip_runtime.h>
#include <stdint.h>

typedef unsigned short u16;
typedef __attribute__((ext_vector_type(8))) __bf16 bf16x8;
typedef __attribute__((ext_vector_type(4))) __bf16 bf16x4;
typedef __attribute__((ext_vector_type(4))) float f32x4;
typedef __attribute__((ext_vector_type(2))) unsigned int u32x2;
typedef __attribute__((ext_vector_type(4))) unsigned int u32x4;

#define QSCALE 0.18033688011112042f /* (1/8) * log2(e) */

__device__ __forceinline__ u16 f2bf(float f) {
    uint32_t u = __builtin_bit_cast(uint32_t, f);
    u = (u + 0x7fffu + ((u >> 16) & 1u)) >> 16;
    return (u16)u;
}

// async global->LDS, 16B/lane; LDS dest = wave-uniform base + lane*16.
__device__ __forceinline__ void gl_lds16(const u16* g, u16* l) {
    __builtin_amdgcn_global_load_lds(
        (__attribute__((address_space(1))) uint32_t*)(g),
        (__attribute__((address_space(3))) uint32_t*)(l), 16, 0, 0);
}

// ---- x (fp32) -> bf16, 4 elems/thread ----
__global__ __launch_bounds__(256) void convert_x_k(const float* __restrict__ xf,
                                                   u16* __restrict__ xbf) {
    const size_t v = (size_t)blockIdx.x * 256 + threadIdx.x; // float4 index
    const f32x4 val = ((const f32x4*)xf)[v];
    u32x2 p;
    p.x = (uint32_t)f2bf(val.x) | ((uint32_t)f2bf(val.y) << 16);
    p.y = (uint32_t)f2bf(val.z) | ((uint32_t)f2bf(val.w) << 16);
    *(u32x2*)&xbf[v * 4] = p;
}

// ---- MFMA GEMM, 2-phase pipelined, B consumed DIRECTLY from fp32 weights
// with in-kernel transpose (B^T[n][k] = W[k][n]; W is L2-resident: wq 3MB,
// wp 1MB < 4MB/XCD). A staged bf16 via gl_lds16 (unchanged). T14 ordering:
// B global loads issued before MFMAs, cvt+ds_write after.
// EPI 0 (BN=128): LDS-bounce epilogue -> fully coalesced dwordx4 stores of
// Q(xQSCALE)/K/Vt (replaces 64 scattered u16 stores/thread; Vt scatter was
// 64 sectors/inst). EPI 1 (BN=64): fp32 out direct.
template <int EPI, int BN>
__global__ __launch_bounds__(256, 3) void gemm_bt_k(
    const u16* __restrict__ A, const float* __restrict__ Bw,
    const float* __restrict__ bias,
    u16* __restrict__ Qb, u16* __restrict__ Kb, u16* __restrict__ Vt,
    float* __restrict__ OutF) {
    constexpr int MI = (BN == 128) ? 4 : 2;
    constexpr int BC = (BN == 128) ? 1536 : 512; // B source row length
    constexpr int NB = BN * 32 / 256;            // B fp32 elems per thread
    constexpr int SSTG = 2 * 128 * 32 + 2 * BN * 32;
    constexpr int SMEM = (EPI == 0) ? (128 * 136 > SSTG ? 128 * 136 : SSTG) : SSTG;
    __shared__ u16 smem[SMEM];
    u16* lA = smem;                  // [2][128*32]
    u16* lB = smem + 2 * 128 * 32;   // [2][BN*32]

    const int tid = threadIdx.x;
    const int w = tid >> 6, l = tid & 63, quad = l >> 4, r = l & 15;
    const int tm = blockIdx.x << 7;
    const int tn = blockIdx.y * BN;
    const int wm = (BN == 128) ? ((w >> 1) << 6) : (w << 5);
    const int wn = (BN == 128) ? ((w & 1) << 6) : 0;
    const int srow = l >> 2, sch = (l & 3) << 3;
    // B-transpose staging mapping: lane covers source row kc, n-strip ng*NB
    const int kc = tid & 31, ng = tid >> 5; // 32 k-rows x 8 n-groups

    f32x4 acc[MI][4];
#pragma unroll
    for (int i = 0; i < MI; ++i)
#pragma unroll
        for (int j = 0; j < 4; ++j) acc[i][j] = (f32x4){0.f, 0.f, 0.f, 0.f};

    auto stageA = [&](int b, int kk) {
#pragma unroll
        for (int ii = 0; ii < 2; ++ii) {
            const int rowl = w * 32 + ii * 16; // wave-uniform
            gl_lds16(A + (size_t)(tm + rowl + srow) * 512 + kk + sch,
                     &lA[b * 4096 + rowl * 32]);
        }
    };

    // ---- prologue: tile 0 ----
    stageA(0, 0);
    {
        const float* bsrc = Bw + (size_t)kc * BC + tn + ng * NB;
        f32x4 br[NB / 4];
#pragma unroll
        for (int j = 0; j < NB / 4; ++j) br[j] = ((const f32x4*)bsrc)[j];
#pragma unroll
        for (int e = 0; e < NB; ++e)
            lB[(ng * NB + e) * 32 + kc] = f2bf(br[e / 4][e & 3]);
    }
    __syncthreads(); // implicit vmcnt(0)+lgkmcnt(0): tile 0 resident

    int cur = 0;
    for (int kk = 0; kk < 512; kk += 32) {
        const bool hn = (kk + 32) < 512;
        f32x4 br[NB / 4];
        if (hn) {
            stageA(cur ^ 1, kk + 32); // async, drains at barrier
            const float* bsrc = Bw + (size_t)(kk + 32 + kc) * BC + tn + ng * NB;
#pragma unroll
            for (int j = 0; j < NB / 4; ++j) br[j] = ((const f32x4*)bsrc)[j];
        }
        bf16x8 af[MI], bfr[4];
#pragma unroll
        for (int mi = 0; mi < MI; ++mi)
            af[mi] = *(const bf16x8*)&lA[cur * 4096 + (wm + mi * 16 + r) * 32 + quad * 8];
#pragma unroll
        for (int ni = 0; ni < 4; ++ni)
            bfr[ni] =
                *(const bf16x8*)&lB[cur * BN * 32 + (wn + ni * 16 + r) * 32 + quad * 8];
#pragma unroll
        for (int mi = 0; mi < MI; ++mi)
#pragma unroll
            for (int ni = 0; ni < 4; ++ni)
                acc[mi][ni] = __builtin_amdgcn_mfma_f32_16x16x32_bf16(
                    af[mi], bfr[ni], acc[mi][ni], 0, 0, 0);
        if (hn) { // B loads' latency hidden under the MFMAs above
            u16* dB = &lB[(cur ^ 1) * BN * 32];
#pragma unroll
            for (int e = 0; e < NB; ++e)
                dB[(ng * NB + e) * 32 + kc] = f2bf(br[e / 4][e & 3]);
        }
        __syncthreads();
        cur ^= 1;
    }

    if (EPI == 1) { // fp32 out, direct (64B runs, adequate)
#pragma unroll
        for (int ni = 0; ni < 4; ++ni) {
            const int n = tn + wn + ni * 16 + r;
            const float bv = bias[n];
#pragma unroll
            for (int mi = 0; mi < MI; ++mi)
#pragma unroll
                for (int i = 0; i < 4; ++i) {
                    const int m = tm + wm + mi * 16 + quad * 4 + i;
                    OutF[(size_t)m * 512 + n] = acc[mi][ni][i] + bv;
                }
        }
    } else {
        // ---- LDS-bounce epilogue: coalesced Q/K/Vt stores ----
        const bool isV = (tn >= 1024);
        const bool isQ = (tn < 512);
#pragma unroll
        for (int ni = 0; ni < 4; ++ni) {
            const int nl = wn + ni * 16 + r;
            const float bv = bias[tn + nl];
#pragma unroll
            for (int mi = 0; mi < MI; ++mi)
#pragma unroll
                for (int i = 0; i < 4; ++i) {
                    const int ml = wm + mi * 16 + quad * 4 + i;
                    float v = acc[mi][ni][i] + bv;
                    if (isQ) v *= QSCALE;
                    const u16 hb = f2bf(v);
                    if (isV)
                        smem[nl * 136 + ml] = hb; // transposed for t-contig rows
                    else
                        smem[ml * 136 + nl] = hb;
                }
        }
        __syncthreads();
        const int tbb = tm >> 11, tt = tm & 2047;
        if (!isV) {
            u16* base = isQ ? Qb : Kb;
            const int mlr = l >> 3, ls = l & 7;
#pragma unroll
            for (int rg = 0; rg < 4; ++rg)
#pragma unroll
                for (int h = 0; h < 2; ++h) {
                    const int ml = (w * 4 + rg) * 8 + mlr;
                    const int head = ((tn + h * 64) >> 6) & 7;
                    const int bh = tbb * 8 + head;
                    const u32x4 dv = *(const u32x4*)&smem[ml * 136 + h * 64 + ls * 8];
                    *(u32x4*)&base[((size_t)(bh * 2048 + tt + ml) << 6) + ls * 8] = dv;
                }
        } else {
            const int nlr = l >> 4, ls = l & 15;
#pragma unroll
            for (int j2 = 0; j2 < 8; ++j2) {
                const int nl = w * 32 + j2 * 4 + nlr;
                const int n = tn + nl;
                const int d = n & 63, head = (n >> 6) & 7;
                const int bh = tbb * 8 + head;
                const u32x4 dv = *(const u32x4*)&smem[nl * 136 + ls * 8];
                *(u32x4*)&Vt[((size_t)(bh * 64 + d) << 11) + tt + ls * 8] = dv;
            }
        }
    }
}

// ---- MFMA flash attention v8 (frozen from R6): 4 waves x 32 q-rows,
// in-register P path via kv-permuted QK, zero bank conflicts, hoisted
// ds_reads, launch_bounds(256,2), cvt_pk bf16 pack.
__global__ __launch_bounds__(256, 2) void attn_k(
    const u16* __restrict__ Qb, const u16* __restrict__ Kb,
    const u16* __restrict__ Vt, u16* __restrict__ attnb) {
    __shared__ u16 lk[2][64 * 64];
    __shared__ u16 lv[2][64 * 64];
    const int tid = threadIdx.x;
    const int w = tid >> 6, l = tid & 63, quad = l >> 4, r = l & 15;
    const int qt = blockIdx.x, bh = blockIdx.y;
    const size_t qbase = (size_t)bh * 2048 + qt * 128;
    const int srl = l >> 3;
    const int sg = (l & 7) ^ srl; // V staging swizzle (unchanged)

    const int rl = r & 7;
    const int rhi = r >> 3;
    // K-read swizzle for permuted rows: s_k = ri ^ ((rr&1)<<1) ^ ((rr&2)<<1)
    const int skq = (r & 3) ^ (((r >> 2) & 1) << 1) ^ (((r >> 2) & 2) << 1);
    const int g0 = (quad ^ skq) << 3; // stored granule (u16 units)

    // Q fragments: 2 q-subtiles x 2 halves of d
    bf16x8 qf[2][2];
#pragma unroll
    for (int qs = 0; qs < 2; ++qs)
#pragma unroll
        for (int hf = 0; hf < 2; ++hf)
            qf[qs][hf] = *(const bf16x8*)&Qb[((qbase + w * 32 + qs * 16 + r) << 6) +
                                            hf * 32 + quad * 8];

    const u32x4 onesu = {0x3F803F80u, 0x3F803F80u, 0x3F803F80u, 0x3F803F80u};
    const bf16x8 vones = __builtin_bit_cast(bf16x8, onesu); // bf16 1.0 x8

    f32x4 o[2][4];
#pragma unroll
    for (int qs = 0; qs < 2; ++qs)
#pragma unroll
        for (int i = 0; i < 4; ++i) o[qs][i] = (f32x4){0.f, 0.f, 0.f, 0.f};
    f32x4 osum[2];
    osum[0] = (f32x4){0.f, 0.f, 0.f, 0.f};
    osum[1] = (f32x4){0.f, 0.f, 0.f, 0.f};

    auto stage = [&](int b, int kv0) {
#pragma unroll
        for (int ii = 0; ii < 2; ++ii) {
            const int chunk = w * 2 + ii;
            // K: source pre-swizzled so stored granule gs holds true granule
            // gs ^ s_k(row); row = chunk*8 + srl.
            const int skr = (srl & 3) ^ ((chunk & 1) << 1) ^ ((chunk & 2) << 1);
            gl_lds16(Kb + ((size_t)(bh * 2048 + kv0 + chunk * 8 + srl) << 6) +
                         ((l & 7) ^ skr) * 8,
                     &lk[b][chunk * 512]);
            gl_lds16(Vt + (((size_t)(bh * 64 + chunk * 8 + srl)) << 11) + kv0 + sg * 8,
                     &lv[b][chunk * 512]);
        }
    };

    stage(0, 0);
    __syncthreads(); // implicit vmcnt(0): tile 0 resident

    int cur = 0;
    for (int kv0 = 0; kv0 < 2048; kv0 += 64) {
        if (kv0 + 64 < 2048) stage(cur ^ 1, kv0 + 64); // flies under compute

        // ---- hoisted LDS reads: all 16 ds_read_b128 issued up front ----
        bf16x8 ka[4], kb[4]; // K fragments (shared across q-subtiles)
#pragma unroll
        for (int kt = 0; kt < 4; ++kt) {
            const int R = (kt & 1) * 32 + (r >> 2) * 8 + (kt >> 1) * 4 + (r & 3);
            ka[kt] = *(const bf16x8*)&lk[cur][R * 64 + g0];
            kb[kt] = *(const bf16x8*)&lk[cur][(R * 64 + g0) ^ 32];
        }
        bf16x8 vb[2][4]; // V^T fragments (shared across q-subtiles)
#pragma unroll
        for (int h = 0; h < 2; ++h)
#pragma unroll
            for (int dt = 0; dt < 4; ++dt) {
                const int baseV = (dt * 2 + rhi) * 512 + rl * 64;
                vb[h][dt] = *(const bf16x8*)&lv[cur][baseV + ((h * 4 + quad) ^ rl) * 8];
            }

        // QK with permuted K rows: lane (quad,r) ends up holding
        // P[q][kv = (kt&1)*32 + quad*8 + (kt>>1)*4 + i]; bf16 via cvt_pk.
        bf16x4 pk4[2][4];
#pragma unroll
        for (int kt = 0; kt < 4; ++kt) {
#pragma unroll
            for (int qs = 0; qs < 2; ++qs) {
                f32x4 z = (f32x4){0.f, 0.f, 0.f, 0.f};
                __builtin_amdgcn_s_setprio(1);
                z = __builtin_amdgcn_mfma_f32_16x16x32_bf16(ka[kt], qf[qs][0], z, 0, 0, 0);
                z = __builtin_amdgcn_mfma_f32_16x16x32_bf16(kb[kt], qf[qs][1], z, 0, 0, 0);
                __builtin_amdgcn_s_setprio(0);
                // p = exp2(s): raw v_exp_f32 (|s|<8); plain casts -> compiler
                // emits v_cvt_pk_bf16_f32 pairs (RNE)
                bf16x4 pb;
                pb[0] = (__bf16)__builtin_amdgcn_exp2f(z[0]);
                pb[1] = (__bf16)__builtin_amdgcn_exp2f(z[1]);
                pb[2] = (__bf16)__builtin_amdgcn_exp2f(z[2]);
                pb[3] = (__bf16)__builtin_amdgcn_exp2f(z[3]);
                pk4[qs][kt] = pb;
            }
        }

        // PV: A-frag[qs][h] = {pk4[qs][h], pk4[qs][h+2]} in registers;
        // B = hoisted V^T fragments; + ones-MFMA row sums
        __builtin_amdgcn_s_setprio(1);
#pragma unroll
        for (int h = 0; h < 2; ++h) {
            const bf16x8 ap0 = __builtin_shufflevector(pk4[0][h], pk4[0][h + 2],
                                                       0, 1, 2, 3, 4, 5, 6, 7);
            const bf16x8 ap1 = __builtin_shufflevector(pk4[1][h], pk4[1][h + 2],
                                                       0, 1, 2, 3, 4, 5, 6, 7);
#pragma unroll
            for (int dt = 0; dt < 4; ++dt) {
                o[0][dt] = __builtin_amdgcn_mfma_f32_16x16x32_bf16(ap0, vb[h][dt],
                                                                  o[0][dt], 0, 0, 0);
                o[1][dt] = __builtin_amdgcn_mfma_f32_16x16x32_bf16(ap1, vb[h][dt],
                                                                  o[1][dt], 0, 0, 0);
            }
            osum[0] = __builtin_amdgcn_mfma_f32_16x16x32_bf16(ap0, vones, osum[0], 0, 0, 0);
            osum[1] = __builtin_amdgcn_mfma_f32_16x16x32_bf16(ap1, vones, osum[1], 0, 0, 0);
        }
        __builtin_amdgcn_s_setprio(0);

        __syncthreads(); // drains next K/V tile loads (flew during QK+exp+PV)
        cur ^= 1;
    }

    const int bb = bh >> 3, head = bh & 7;
#pragma unroll
    for (int qs = 0; qs < 2; ++qs) {
#pragma unroll
        for (int i = 0; i < 4; ++i) {
            const float inv = __builtin_amdgcn_rcpf(osum[qs][i]); // <=1 ulp, fine
            const int row = bb * 2048 + qt * 128 + w * 32 + qs * 16 + quad * 4 + i;
#pragma unroll
            for (int dt = 0; dt < 4; ++dt)
                attnb[(size_t)row * 512 + head * 64 + dt * 16 + r] =
                    f2bf(o[qs][dt][i] * inv);
        }
    }
}

// ---------------- launch ----------------
extern "C" void kernel_launch(void* const* d_in, const int* in_sizes, int n_in,
                              void* d_out, int out_size, void* d_ws, size_t ws_size,
                              hipStream_t stream) {
    const float *x = nullptr, *wq = nullptr, *bq = nullptr, *wp = nullptr, *bp = nullptr;
    for (int i = 0; i < n_in; ++i) {
        switch (in_sizes[i]) {
            case 4194304: x  = (const float*)d_in[i]; break;
            case 786432:  wq = (const float*)d_in[i]; break;
            case 1536:    bq = (const float*)d_in[i]; break;
            case 262144:  wp = (const float*)d_in[i]; break;
            case 512:     bp = (const float*)d_in[i]; break;
        }
    }
    if (!x || !wq || !bq || !wp || !bp) {
        x = (const float*)d_in[0]; wq = (const float*)d_in[1];
        bq = (const float*)d_in[2]; wp = (const float*)d_in[3];
        bp = (const float*)d_in[4];
    }
    float* out = (float*)d_out;

    // ws plan (32 MiB): attnb@0, Qb@8M, Kb@16M, Vt@24M. xbf lives in d_out
    // until proj. Weight transposes are gone (B consumed fp32 in-kernel).
    char* ws = (char*)d_ws;
    u16* attnb  = (u16*)(ws + 0);
    u16* Qb     = (u16*)(ws + 8388608);
    u16* Kb     = (u16*)(ws + 16777216);
    u16* Vt     = (u16*)(ws + 25165824);
    u16* xbf    = (u16*)d_out;

    convert_x_k<<<dim3(4096), 256, 0, stream>>>(x, xbf);
    gemm_bt_k<0, 128><<<dim3(64, 12), 256, 0, stream>>>(xbf, wq, bq, Qb, Kb, Vt,
                                                        nullptr);
    attn_k<<<dim3(16, 32), 256, 0, stream>>>(Qb, Kb, Vt, attnb);
    gemm_bt_k<1, 64><<<dim3(64, 8), 256, 0, stream>>>(attnb, wp, bp, nullptr, nullptr,
                                                      nullptr, out);
}

// Round 9
// 157.597 us; speedup vs baseline: 1.0842x; 1.0842x over previous
//
#include <hip/hip_runtime.h>
#include <stdint.h>

typedef unsigned short u16;
typedef __attribute__((ext_vector_type(8))) __bf16 bf16x8;
typedef __attribute__((ext_vector_type(4))) __bf16 bf16x4;
typedef __attribute__((ext_vector_type(4))) float f32x4;
typedef __attribute__((ext_vector_type(2))) unsigned int u32x2;
typedef __attribute__((ext_vector_type(4))) unsigned int u32x4;

#define QSCALE 0.18033688011112042f /* (1/8) * log2(e) */

__device__ __forceinline__ u16 f2bf(float f) {
    uint32_t u = __builtin_bit_cast(uint32_t, f);
    u = (u + 0x7fffu + ((u >> 16) & 1u)) >> 16;
    return (u16)u;
}

// async global->LDS, 16B/lane; LDS dest = wave-uniform base + lane*16.
__device__ __forceinline__ void gl_lds16(const u16* g, u16* l) {
    __builtin_amdgcn_global_load_lds(
        (__attribute__((address_space(1))) uint32_t*)(g),
        (__attribute__((address_space(3))) uint32_t*)(l), 16, 0, 0);
}

// ---- fused prep: x fp32->bf16 (blocks 0..4095) + wqkv transpose-cvt
// (blocks 4096..4287). wp transpose stays post-attn (wprojT aliases Qb).
__global__ __launch_bounds__(256) void prep_k(const float* __restrict__ xf,
                                              u16* __restrict__ xbf,
                                              const float* __restrict__ wq,
                                              u16* __restrict__ wqkvT) {
    __shared__ u16 t[64][65];
    const int b = blockIdx.x;
    const int tid = threadIdx.x;
    if (b < 4096) {
        const size_t v = (size_t)b * 256 + tid; // float4 index
        const f32x4 val = ((const f32x4*)xf)[v];
        u32x2 p;
        p.x = (uint32_t)f2bf(val.x) | ((uint32_t)f2bf(val.y) << 16);
        p.y = (uint32_t)f2bf(val.z) | ((uint32_t)f2bf(val.w) << 16);
        *(u32x2*)&xbf[v * 4] = p;
    } else {
        const int bb = b - 4096; // 24 x 8 tiles over [512][1536]
        const int bx = (bb % 24) << 6, by = (bb / 24) << 6;
        const int tx = tid & 63, ty = tid >> 6; // 64 x 4
#pragma unroll
        for (int i = ty; i < 64; i += 4)
            t[i][tx] = f2bf(wq[(size_t)(by + i) * 1536 + bx + tx]);
        __syncthreads();
#pragma unroll
        for (int i = ty; i < 64; i += 4)
            wqkvT[(size_t)(bx + i) * 512 + by + tx] = t[tx][i];
    }
}

// ---- weight transpose + cvt: in fp32[R][C] -> out bf16[C][R], 64x64 tiles ----
__global__ void transpose_cvt_k(const float* __restrict__ in,
                                u16* __restrict__ out, int R, int C) {
    __shared__ u16 t[64][65];
    const int bx = blockIdx.x << 6, by = blockIdx.y << 6;
    const int tx = threadIdx.x, ty = threadIdx.y; // 64 x 8
#pragma unroll
    for (int i = ty; i < 64; i += 8)
        t[i][tx] = f2bf(in[(size_t)(by + i) * C + bx + tx]);
    __syncthreads();
#pragma unroll
    for (int i = ty; i < 64; i += 8) out[(size_t)(bx + i) * R + by + tx] = t[tx][i];
}

// ---- m97-style MFMA GEMM, 2-phase pipelined (R7's proven loop: bf16 Bt,
// gl_lds16 for BOTH A and B; R8's reg-staged fp32-B was a 17-20us
// regression -- 16 f2bf + 16 ds_write_b16 per thread per K-step).
// Tile 128 x BN; BN=64 stacks waves in M for 2x grid density (gemm1).
// EPI 0: LDS-bounce epilogue -> coalesced dwordx4 Q(xQSCALE)/K/Vt stores
// (R8-validated; replaces 64-sector/inst Vt scatter). EPI 1: fp32 direct.
template <int EPI, int BN>
__global__ __launch_bounds__(256, 3) void gemm_bt_k(
    const u16* __restrict__ A, const u16* __restrict__ Bt,
    const float* __restrict__ bias,
    u16* __restrict__ Qb, u16* __restrict__ Kb, u16* __restrict__ Vt,
    float* __restrict__ OutF) {
    constexpr int MI = (BN == 128) ? 4 : 2;
    constexpr int SSTG = 2 * 128 * 32 + 2 * BN * 32; // u16 units
    constexpr int SEPI = (EPI == 0) ? 128 * 136 : 0;
    constexpr int SMEM = SSTG > SEPI ? SSTG : SEPI;
    __shared__ u16 smem[SMEM];
    u16* lA = smem;                // [2][128*32]
    u16* lB = smem + 2 * 128 * 32; // [2][BN*32]

    const int tid = threadIdx.x;
    const int w = tid >> 6, l = tid & 63, quad = l >> 4, r = l & 15;
    const int tm = blockIdx.x << 7;
    const int tn = blockIdx.y * BN;
    const int wm = (BN == 128) ? ((w >> 1) << 6) : (w << 5);
    const int wn = (BN == 128) ? ((w & 1) << 6) : 0;
    const int srow = l >> 2, sch = (l & 3) << 3;

    f32x4 acc[MI][4];
#pragma unroll
    for (int i = 0; i < MI; ++i)
#pragma unroll
        for (int j = 0; j < 4; ++j) acc[i][j] = (f32x4){0.f, 0.f, 0.f, 0.f};

    auto stage = [&](int b, int kk) {
#pragma unroll
        for (int ii = 0; ii < 2; ++ii) {
            const int rowl = w * 32 + ii * 16; // wave-uniform
            gl_lds16(A + (size_t)(tm + rowl + srow) * 512 + kk + sch,
                     &lA[b * 4096 + rowl * 32]);
        }
        if (BN == 128) {
#pragma unroll
            for (int ii = 0; ii < 2; ++ii) {
                const int rowl = w * 32 + ii * 16;
                gl_lds16(Bt + (size_t)(tn + rowl + srow) * 512 + kk + sch,
                         &lB[b * BN * 32 + rowl * 32]);
            }
        } else {
            const int rowl = w * 16;
            gl_lds16(Bt + (size_t)(tn + rowl + srow) * 512 + kk + sch,
                     &lB[b * BN * 32 + rowl * 32]);
        }
    };

    stage(0, 0);
    __syncthreads(); // implicit vmcnt(0): tile 0 resident

    int cur = 0;
    for (int kk = 0; kk < 512; kk += 32) {
        if (kk + 32 < 512) stage(cur ^ 1, kk + 32); // in flight during compute
        bf16x8 af[MI], bfr[4];
#pragma unroll
        for (int mi = 0; mi < MI; ++mi)
            af[mi] =
                *(const bf16x8*)&lA[cur * 4096 + (wm + mi * 16 + r) * 32 + quad * 8];
#pragma unroll
        for (int ni = 0; ni < 4; ++ni)
            bfr[ni] =
                *(const bf16x8*)&lB[cur * BN * 32 + (wn + ni * 16 + r) * 32 + quad * 8];
#pragma unroll
        for (int mi = 0; mi < MI; ++mi)
#pragma unroll
            for (int ni = 0; ni < 4; ++ni)
                acc[mi][ni] = __builtin_amdgcn_mfma_f32_16x16x32_bf16(
                    af[mi], bfr[ni], acc[mi][ni], 0, 0, 0);
        __syncthreads(); // drains next-tile loads (flew during MFMAs) + frag reads
        cur ^= 1;
    }

    if (EPI == 1) { // fp32 out, direct (64B runs, adequate)
#pragma unroll
        for (int ni = 0; ni < 4; ++ni) {
            const int n = tn + wn + ni * 16 + r;
            const float bv = bias[n];
#pragma unroll
            for (int mi = 0; mi < MI; ++mi)
#pragma unroll
                for (int i = 0; i < 4; ++i) {
                    const int m = tm + wm + mi * 16 + quad * 4 + i;
                    OutF[(size_t)m * 512 + n] = acc[mi][ni][i] + bv;
                }
        }
    } else {
        // ---- LDS-bounce epilogue (R8-validated): coalesced Q/K/Vt stores ----
        const bool isV = (tn >= 1024);
        const bool isQ = (tn < 512);
#pragma unroll
        for (int ni = 0; ni < 4; ++ni) {
            const int nl = wn + ni * 16 + r;
            const float bv = bias[tn + nl];
#pragma unroll
            for (int mi = 0; mi < MI; ++mi)
#pragma unroll
                for (int i = 0; i < 4; ++i) {
                    const int ml = wm + mi * 16 + quad * 4 + i;
                    float v = acc[mi][ni][i] + bv;
                    if (isQ) v *= QSCALE;
                    const u16 hb = f2bf(v);
                    if (isV)
                        smem[nl * 136 + ml] = hb; // transposed for t-contig rows
                    else
                        smem[ml * 136 + nl] = hb;
                }
        }
        __syncthreads();
        const int tbb = tm >> 11, tt = tm & 2047;
        if (!isV) {
            u16* base = isQ ? Qb : Kb;
            const int mlr = l >> 3, ls = l & 7;
#pragma unroll
            for (int rg = 0; rg < 4; ++rg)
#pragma unroll
                for (int h = 0; h < 2; ++h) {
                    const int ml = (w * 4 + rg) * 8 + mlr;
                    const int head = ((tn + h * 64) >> 6) & 7;
                    const int bh = tbb * 8 + head;
                    const u32x4 dv = *(const u32x4*)&smem[ml * 136 + h * 64 + ls * 8];
                    *(u32x4*)&base[((size_t)(bh * 2048 + tt + ml) << 6) + ls * 8] = dv;
                }
        } else {
            const int nlr = l >> 4, ls = l & 15;
#pragma unroll
            for (int j2 = 0; j2 < 8; ++j2) {
                const int nl = w * 32 + j2 * 4 + nlr;
                const int n = tn + nl;
                const int d = n & 63, head = (n >> 6) & 7;
                const int bh = tbb * 8 + head;
                const u32x4 dv = *(const u32x4*)&smem[nl * 136 + ls * 8];
                *(u32x4*)&Vt[((size_t)(bh * 64 + d) << 11) + tt + ls * 8] = dv;
            }
        }
    }
}

// ---- MFMA flash attention v8 (frozen from R6): 4 waves x 32 q-rows,
// in-register P path via kv-permuted QK, zero bank conflicts, hoisted
// ds_reads, launch_bounds(256,2), cvt_pk bf16 pack.
__global__ __launch_bounds__(256, 2) void attn_k(
    const u16* __restrict__ Qb, const u16* __restrict__ Kb,
    const u16* __restrict__ Vt, u16* __restrict__ attnb) {
    __shared__ u16 lk[2][64 * 64];
    __shared__ u16 lv[2][64 * 64];
    const int tid = threadIdx.x;
    const int w = tid >> 6, l = tid & 63, quad = l >> 4, r = l & 15;
    const int qt = blockIdx.x, bh = blockIdx.y;
    const size_t qbase = (size_t)bh * 2048 + qt * 128;
    const int srl = l >> 3;
    const int sg = (l & 7) ^ srl; // V staging swizzle (unchanged)

    const int rl = r & 7;
    const int rhi = r >> 3;
    // K-read swizzle for permuted rows: s_k = ri ^ ((rr&1)<<1) ^ ((rr&2)<<1)
    const int skq = (r & 3) ^ (((r >> 2) & 1) << 1) ^ (((r >> 2) & 2) << 1);
    const int g0 = (quad ^ skq) << 3; // stored granule (u16 units)

    // Q fragments: 2 q-subtiles x 2 halves of d
    bf16x8 qf[2][2];
#pragma unroll
    for (int qs = 0; qs < 2; ++qs)
#pragma unroll
        for (int hf = 0; hf < 2; ++hf)
            qf[qs][hf] = *(const bf16x8*)&Qb[((qbase + w * 32 + qs * 16 + r) << 6) +
                                            hf * 32 + quad * 8];

    const u32x4 onesu = {0x3F803F80u, 0x3F803F80u, 0x3F803F80u, 0x3F803F80u};
    const bf16x8 vones = __builtin_bit_cast(bf16x8, onesu); // bf16 1.0 x8

    f32x4 o[2][4];
#pragma unroll
    for (int qs = 0; qs < 2; ++qs)
#pragma unroll
        for (int i = 0; i < 4; ++i) o[qs][i] = (f32x4){0.f, 0.f, 0.f, 0.f};
    f32x4 osum[2];
    osum[0] = (f32x4){0.f, 0.f, 0.f, 0.f};
    osum[1] = (f32x4){0.f, 0.f, 0.f, 0.f};

    auto stage = [&](int b, int kv0) {
#pragma unroll
        for (int ii = 0; ii < 2; ++ii) {
            const int chunk = w * 2 + ii;
            // K: source pre-swizzled so stored granule gs holds true granule
            // gs ^ s_k(row); row = chunk*8 + srl.
            const int skr = (srl & 3) ^ ((chunk & 1) << 1) ^ ((chunk & 2) << 1);
            gl_lds16(Kb + ((size_t)(bh * 2048 + kv0 + chunk * 8 + srl) << 6) +
                         ((l & 7) ^ skr) * 8,
                     &lk[b][chunk * 512]);
            gl_lds16(Vt + (((size_t)(bh * 64 + chunk * 8 + srl)) << 11) + kv0 + sg * 8,
                     &lv[b][chunk * 512]);
        }
    };

    stage(0, 0);
    __syncthreads(); // implicit vmcnt(0): tile 0 resident

    int cur = 0;
    for (int kv0 = 0; kv0 < 2048; kv0 += 64) {
        if (kv0 + 64 < 2048) stage(cur ^ 1, kv0 + 64); // flies under compute

        // ---- hoisted LDS reads: all 16 ds_read_b128 issued up front ----
        bf16x8 ka[4], kb[4]; // K fragments (shared across q-subtiles)
#pragma unroll
        for (int kt = 0; kt < 4; ++kt) {
            const int R = (kt & 1) * 32 + (r >> 2) * 8 + (kt >> 1) * 4 + (r & 3);
            ka[kt] = *(const bf16x8*)&lk[cur][R * 64 + g0];
            kb[kt] = *(const bf16x8*)&lk[cur][(R * 64 + g0) ^ 32];
        }
        bf16x8 vb[2][4]; // V^T fragments (shared across q-subtiles)
#pragma unroll
        for (int h = 0; h < 2; ++h)
#pragma unroll
            for (int dt = 0; dt < 4; ++dt) {
                const int baseV = (dt * 2 + rhi) * 512 + rl * 64;
                vb[h][dt] = *(const bf16x8*)&lv[cur][baseV + ((h * 4 + quad) ^ rl) * 8];
            }

        // QK with permuted K rows: lane (quad,r) ends up holding
        // P[q][kv = (kt&1)*32 + quad*8 + (kt>>1)*4 + i]; bf16 via cvt_pk.
        bf16x4 pk4[2][4];
#pragma unroll
        for (int kt = 0; kt < 4; ++kt) {
#pragma unroll
            for (int qs = 0; qs < 2; ++qs) {
                f32x4 z = (f32x4){0.f, 0.f, 0.f, 0.f};
                __builtin_amdgcn_s_setprio(1);
                z = __builtin_amdgcn_mfma_f32_16x16x32_bf16(ka[kt], qf[qs][0], z, 0, 0, 0);
                z = __builtin_amdgcn_mfma_f32_16x16x32_bf16(kb[kt], qf[qs][1], z, 0, 0, 0);
                __builtin_amdgcn_s_setprio(0);
                // p = exp2(s): raw v_exp_f32 (|s|<8); plain casts -> compiler
                // emits v_cvt_pk_bf16_f32 pairs (RNE)
                bf16x4 pb;
                pb[0] = (__bf16)__builtin_amdgcn_exp2f(z[0]);
                pb[1] = (__bf16)__builtin_amdgcn_exp2f(z[1]);
                pb[2] = (__bf16)__builtin_amdgcn_exp2f(z[2]);
                pb[3] = (__bf16)__builtin_amdgcn_exp2f(z[3]);
                pk4[qs][kt] = pb;
            }
        }

        // PV: A-frag[qs][h] = {pk4[qs][h], pk4[qs][h+2]} in registers;
        // B = hoisted V^T fragments; + ones-MFMA row sums
        __builtin_amdgcn_s_setprio(1);
#pragma unroll
        for (int h = 0; h < 2; ++h) {
            const bf16x8 ap0 = __builtin_shufflevector(pk4[0][h], pk4[0][h + 2],
                                                       0, 1, 2, 3, 4, 5, 6, 7);
            const bf16x8 ap1 = __builtin_shufflevector(pk4[1][h], pk4[1][h + 2],
                                                       0, 1, 2, 3, 4, 5, 6, 7);
#pragma unroll
            for (int dt = 0; dt < 4; ++dt) {
                o[0][dt] = __builtin_amdgcn_mfma_f32_16x16x32_bf16(ap0, vb[h][dt],
                                                                  o[0][dt], 0, 0, 0);
                o[1][dt] = __builtin_amdgcn_mfma_f32_16x16x32_bf16(ap1, vb[h][dt],
                                                                  o[1][dt], 0, 0, 0);
            }
            osum[0] = __builtin_amdgcn_mfma_f32_16x16x32_bf16(ap0, vones, osum[0], 0, 0, 0);
            osum[1] = __builtin_amdgcn_mfma_f32_16x16x32_bf16(ap1, vones, osum[1], 0, 0, 0);
        }
        __builtin_amdgcn_s_setprio(0);

        __syncthreads(); // drains next K/V tile loads (flew during QK+exp+PV)
        cur ^= 1;
    }

    const int bb = bh >> 3, head = bh & 7;
#pragma unroll
    for (int qs = 0; qs < 2; ++qs) {
#pragma unroll
        for (int i = 0; i < 4; ++i) {
            const float inv = __builtin_amdgcn_rcpf(osum[qs][i]); // <=1 ulp, fine
            const int row = bb * 2048 + qt * 128 + w * 32 + qs * 16 + quad * 4 + i;
#pragma unroll
            for (int dt = 0; dt < 4; ++dt)
                attnb[(size_t)row * 512 + head * 64 + dt * 16 + r] =
                    f2bf(o[qs][dt][i] * inv);
        }
    }
}

// ---------------- launch ----------------
extern "C" void kernel_launch(void* const* d_in, const int* in_sizes, int n_in,
                              void* d_out, int out_size, void* d_ws, size_t ws_size,
                              hipStream_t stream) {
    const float *x = nullptr, *wq = nullptr, *bq = nullptr, *wp = nullptr, *bp = nullptr;
    for (int i = 0; i < n_in; ++i) {
        switch (in_sizes[i]) {
            case 4194304: x  = (const float*)d_in[i]; break;
            case 786432:  wq = (const float*)d_in[i]; break;
            case 1536:    bq = (const float*)d_in[i]; break;
            case 262144:  wp = (const float*)d_in[i]; break;
            case 512:     bp = (const float*)d_in[i]; break;
        }
    }
    if (!x || !wq || !bq || !wp || !bp) {
        x = (const float*)d_in[0]; wq = (const float*)d_in[1];
        bq = (const float*)d_in[2]; wp = (const float*)d_in[3];
        bp = (const float*)d_in[4];
    }
    float* out = (float*)d_out;

    // ws plan (32 MiB): attnb@0 (wqkvT aliases until attn), Qb@8M (wprojT
    // aliases after attn), Kb@16M, Vt@24M. xbf lives in d_out until proj.
    char* ws = (char*)d_ws;
    u16* attnb  = (u16*)(ws + 0);
    u16* wqkvT  = (u16*)(ws + 0);
    u16* Qb     = (u16*)(ws + 8388608);
    u16* wprojT = (u16*)(ws + 8388608);
    u16* Kb     = (u16*)(ws + 16777216);
    u16* Vt     = (u16*)(ws + 25165824);
    u16* xbf    = (u16*)d_out;

    prep_k<<<dim3(4288), 256, 0, stream>>>(x, xbf, wq, wqkvT);
    gemm_bt_k<0, 128><<<dim3(64, 12), 256, 0, stream>>>(xbf, wqkvT, bq, Qb, Kb, Vt,
                                                        nullptr);
    attn_k<<<dim3(16, 32), 256, 0, stream>>>(Qb, Kb, Vt, attnb);
    transpose_cvt_k<<<dim3(8, 8), dim3(64, 8), 0, stream>>>(wp, wprojT, 512, 512);
    gemm_bt_k<1, 64><<<dim3(64, 8), 256, 0, stream>>>(attnb, wprojT, bp, nullptr,
                                                      nullptr, nullptr, out);
}

// Round 10
// 153.255 us; speedup vs baseline: 1.1149x; 1.0283x over previous
//
#include <hip/hip_runtime.h>
#include <stdint.h>

typedef unsigned short u16;
typedef __attribute__((ext_vector_type(8))) __bf16 bf16x8;
typedef __attribute__((ext_vector_type(4))) __bf16 bf16x4;
typedef __attribute__((ext_vector_type(4))) float f32x4;
typedef __attribute__((ext_vector_type(2))) unsigned int u32x2;
typedef __attribute__((ext_vector_type(4))) unsigned int u32x4;

#define QSCALE 0.18033688011112042f /* (1/8) * log2(e) */

__device__ __forceinline__ u16 f2bf(float f) {
    uint32_t u = __builtin_bit_cast(uint32_t, f);
    u = (u + 0x7fffu + ((u >> 16) & 1u)) >> 16;
    return (u16)u;
}

// async global->LDS, 16B/lane; LDS dest = wave-uniform base + lane*16.
__device__ __forceinline__ void gl_lds16(const u16* g, u16* l) {
    __builtin_amdgcn_global_load_lds(
        (__attribute__((address_space(1))) uint32_t*)(g),
        (__attribute__((address_space(3))) uint32_t*)(l), 16, 0, 0);
}

// ---- fused prep: x fp32->bf16 (blocks 0..4095) + wqkv transpose-cvt
// (blocks 4096..4287). wp transpose stays post-attn (wprojT aliases Qb).
__global__ __launch_bounds__(256) void prep_k(const float* __restrict__ xf,
                                              u16* __restrict__ xbf,
                                              const float* __restrict__ wq,
                                              u16* __restrict__ wqkvT) {
    __shared__ u16 t[64][65];
    const int b = blockIdx.x;
    const int tid = threadIdx.x;
    if (b < 4096) {
        const size_t v = (size_t)b * 256 + tid; // float4 index
        const f32x4 val = ((const f32x4*)xf)[v];
        u32x2 p;
        p.x = (uint32_t)f2bf(val.x) | ((uint32_t)f2bf(val.y) << 16);
        p.y = (uint32_t)f2bf(val.z) | ((uint32_t)f2bf(val.w) << 16);
        *(u32x2*)&xbf[v * 4] = p;
    } else {
        const int bb = b - 4096; // 24 x 8 tiles over [512][1536]
        const int bx = (bb % 24) << 6, by = (bb / 24) << 6;
        const int tx = tid & 63, ty = tid >> 6; // 64 x 4
#pragma unroll
        for (int i = ty; i < 64; i += 4)
            t[i][tx] = f2bf(wq[(size_t)(by + i) * 1536 + bx + tx]);
        __syncthreads();
#pragma unroll
        for (int i = ty; i < 64; i += 4)
            wqkvT[(size_t)(bx + i) * 512 + by + tx] = t[tx][i];
    }
}

// ---- weight transpose + cvt: in fp32[R][C] -> out bf16[C][R], 64x64 tiles ----
__global__ void transpose_cvt_k(const float* __restrict__ in,
                                u16* __restrict__ out, int R, int C) {
    __shared__ u16 t[64][65];
    const int bx = blockIdx.x << 6, by = blockIdx.y << 6;
    const int tx = threadIdx.x, ty = threadIdx.y; // 64 x 8
#pragma unroll
    for (int i = ty; i < 64; i += 8)
        t[i][tx] = f2bf(in[(size_t)(by + i) * C + bx + tx]);
    __syncthreads();
#pragma unroll
    for (int i = ty; i < 64; i += 8) out[(size_t)(bx + i) * R + by + tx] = t[tx][i];
}

// ---- m97-style MFMA GEMM, 2-phase pipelined (R7 loop, R9 epilogue).
// EPI 0: LDS-bounce -> coalesced dwordx4 Q(xQSCALE)/K/Vt. EPI 1: fp32 direct.
template <int EPI, int BN>
__global__ __launch_bounds__(256, 3) void gemm_bt_k(
    const u16* __restrict__ A, const u16* __restrict__ Bt,
    const float* __restrict__ bias,
    u16* __restrict__ Qb, u16* __restrict__ Kb, u16* __restrict__ Vt,
    float* __restrict__ OutF) {
    constexpr int MI = (BN == 128) ? 4 : 2;
    constexpr int SSTG = 2 * 128 * 32 + 2 * BN * 32; // u16 units
    constexpr int SEPI = (EPI == 0) ? 128 * 136 : 0;
    constexpr int SMEM = SSTG > SEPI ? SSTG : SEPI;
    __shared__ u16 smem[SMEM];
    u16* lA = smem;                // [2][128*32]
    u16* lB = smem + 2 * 128 * 32; // [2][BN*32]

    const int tid = threadIdx.x;
    const int w = tid >> 6, l = tid & 63, quad = l >> 4, r = l & 15;
    const int tm = blockIdx.x << 7;
    const int tn = blockIdx.y * BN;
    const int wm = (BN == 128) ? ((w >> 1) << 6) : (w << 5);
    const int wn = (BN == 128) ? ((w & 1) << 6) : 0;
    const int srow = l >> 2, sch = (l & 3) << 3;

    f32x4 acc[MI][4];
#pragma unroll
    for (int i = 0; i < MI; ++i)
#pragma unroll
        for (int j = 0; j < 4; ++j) acc[i][j] = (f32x4){0.f, 0.f, 0.f, 0.f};

    auto stage = [&](int b, int kk) {
#pragma unroll
        for (int ii = 0; ii < 2; ++ii) {
            const int rowl = w * 32 + ii * 16; // wave-uniform
            gl_lds16(A + (size_t)(tm + rowl + srow) * 512 + kk + sch,
                     &lA[b * 4096 + rowl * 32]);
        }
        if (BN == 128) {
#pragma unroll
            for (int ii = 0; ii < 2; ++ii) {
                const int rowl = w * 32 + ii * 16;
                gl_lds16(Bt + (size_t)(tn + rowl + srow) * 512 + kk + sch,
                         &lB[b * BN * 32 + rowl * 32]);
            }
        } else {
            const int rowl = w * 16;
            gl_lds16(Bt + (size_t)(tn + rowl + srow) * 512 + kk + sch,
                     &lB[b * BN * 32 + rowl * 32]);
        }
    };

    stage(0, 0);
    __syncthreads(); // implicit vmcnt(0): tile 0 resident

    int cur = 0;
    for (int kk = 0; kk < 512; kk += 32) {
        if (kk + 32 < 512) stage(cur ^ 1, kk + 32); // in flight during compute
        bf16x8 af[MI], bfr[4];
#pragma unroll
        for (int mi = 0; mi < MI; ++mi)
            af[mi] =
                *(const bf16x8*)&lA[cur * 4096 + (wm + mi * 16 + r) * 32 + quad * 8];
#pragma unroll
        for (int ni = 0; ni < 4; ++ni)
            bfr[ni] =
                *(const bf16x8*)&lB[cur * BN * 32 + (wn + ni * 16 + r) * 32 + quad * 8];
#pragma unroll
        for (int mi = 0; mi < MI; ++mi)
#pragma unroll
            for (int ni = 0; ni < 4; ++ni)
                acc[mi][ni] = __builtin_amdgcn_mfma_f32_16x16x32_bf16(
                    af[mi], bfr[ni], acc[mi][ni], 0, 0, 0);
        __syncthreads(); // drains next-tile loads (flew during MFMAs) + frag reads
        cur ^= 1;
    }

    if (EPI == 1) { // fp32 out, direct (64B runs, adequate)
#pragma unroll
        for (int ni = 0; ni < 4; ++ni) {
            const int n = tn + wn + ni * 16 + r;
            const float bv = bias[n];
#pragma unroll
            for (int mi = 0; mi < MI; ++mi)
#pragma unroll
                for (int i = 0; i < 4; ++i) {
                    const int m = tm + wm + mi * 16 + quad * 4 + i;
                    OutF[(size_t)m * 512 + n] = acc[mi][ni][i] + bv;
                }
        }
    } else {
        // ---- LDS-bounce epilogue: coalesced Q/K/Vt stores ----
        const bool isV = (tn >= 1024);
        const bool isQ = (tn < 512);
#pragma unroll
        for (int ni = 0; ni < 4; ++ni) {
            const int nl = wn + ni * 16 + r;
            const float bv = bias[tn + nl];
#pragma unroll
            for (int mi = 0; mi < MI; ++mi)
#pragma unroll
                for (int i = 0; i < 4; ++i) {
                    const int ml = wm + mi * 16 + quad * 4 + i;
                    float v = acc[mi][ni][i] + bv;
                    if (isQ) v *= QSCALE;
                    const u16 hb = f2bf(v);
                    if (isV)
                        smem[nl * 136 + ml] = hb; // transposed for t-contig rows
                    else
                        smem[ml * 136 + nl] = hb;
                }
        }
        __syncthreads();
        const int tbb = tm >> 11, tt = tm & 2047;
        if (!isV) {
            u16* base = isQ ? Qb : Kb;
            const int mlr = l >> 3, ls = l & 7;
#pragma unroll
            for (int rg = 0; rg < 4; ++rg)
#pragma unroll
                for (int h = 0; h < 2; ++h) {
                    const int ml = (w * 4 + rg) * 8 + mlr;
                    const int head = ((tn + h * 64) >> 6) & 7;
                    const int bh = tbb * 8 + head;
                    const u32x4 dv = *(const u32x4*)&smem[ml * 136 + h * 64 + ls * 8];
                    *(u32x4*)&base[((size_t)(bh * 2048 + tt + ml) << 6) + ls * 8] = dv;
                }
        } else {
            const int nlr = l >> 4, ls = l & 15;
#pragma unroll
            for (int j2 = 0; j2 < 8; ++j2) {
                const int nl = w * 32 + j2 * 4 + nlr;
                const int n = tn + nl;
                const int d = n & 63, head = (n >> 6) & 7;
                const int bh = tbb * 8 + head;
                const u32x4 dv = *(const u32x4*)&smem[nl * 136 + ls * 8];
                *(u32x4*)&Vt[((size_t)(bh * 64 + d) << 11) + tt + ls * 8] = dv;
            }
        }
    }
}

// ---- MFMA flash attention v9: v8 + cross-barrier K-fragment register
// prefetch. 3 staging buffers, stage 2 tiles ahead; K-frags for iter t+1
// are ds_read during iter t (overlapping PV), so QK at t starts instantly
// on registers instead of stalling ~load-latency after the barrier (the
// measured ~35% idle). Two named frag sets + unroll-2 (rule #20). One
// __syncthreads/iter (drains stage(t+2); tile t+1 had a full iter of
// flight). LDS 48KB -> still 2 blocks/CU (grid-limited).
__global__ __launch_bounds__(256, 2) void attn_k(
    const u16* __restrict__ Qb, const u16* __restrict__ Kb,
    const u16* __restrict__ Vt, u16* __restrict__ attnb) {
    __shared__ u16 lk[3][64 * 64];
    __shared__ u16 lv[3][64 * 64];
    const int tid = threadIdx.x;
    const int w = tid >> 6, l = tid & 63, quad = l >> 4, r = l & 15;
    const int qt = blockIdx.x, bh = blockIdx.y;
    const size_t qbase = (size_t)bh * 2048 + qt * 128;
    const int srl = l >> 3;
    const int sg = (l & 7) ^ srl; // V staging swizzle

    const int rl = r & 7;
    const int rhi = r >> 3;
    // K-read swizzle for permuted rows
    const int skq = (r & 3) ^ (((r >> 2) & 1) << 1) ^ (((r >> 2) & 2) << 1);
    const int g0 = (quad ^ skq) << 3; // stored granule (u16 units)

    // Q fragments: 2 q-subtiles x 2 halves of d
    bf16x8 qf[2][2];
#pragma unroll
    for (int qs = 0; qs < 2; ++qs)
#pragma unroll
        for (int hf = 0; hf < 2; ++hf)
            qf[qs][hf] = *(const bf16x8*)&Qb[((qbase + w * 32 + qs * 16 + r) << 6) +
                                            hf * 32 + quad * 8];

    const u32x4 onesu = {0x3F803F80u, 0x3F803F80u, 0x3F803F80u, 0x3F803F80u};
    const bf16x8 vones = __builtin_bit_cast(bf16x8, onesu); // bf16 1.0 x8

    f32x4 o[2][4];
#pragma unroll
    for (int qs = 0; qs < 2; ++qs)
#pragma unroll
        for (int i = 0; i < 4; ++i) o[qs][i] = (f32x4){0.f, 0.f, 0.f, 0.f};
    f32x4 osum[2];
    osum[0] = (f32x4){0.f, 0.f, 0.f, 0.f};
    osum[1] = (f32x4){0.f, 0.f, 0.f, 0.f};

    auto stage = [&](int b, int kv0) {
#pragma unroll
        for (int ii = 0; ii < 2; ++ii) {
            const int chunk = w * 2 + ii;
            const int skr = (srl & 3) ^ ((chunk & 1) << 1) ^ ((chunk & 2) << 1);
            gl_lds16(Kb + ((size_t)(bh * 2048 + kv0 + chunk * 8 + srl) << 6) +
                         ((l & 7) ^ skr) * 8,
                     &lk[b][chunk * 512]);
            gl_lds16(Vt + (((size_t)(bh * 64 + chunk * 8 + srl)) << 11) + kv0 + sg * 8,
                     &lv[b][chunk * 512]);
        }
    };

    // per-lane K-frag offsets (kv-permuted rows), compile-time per kt
    int Roff[4];
#pragma unroll
    for (int kt = 0; kt < 4; ++kt) {
        const int R = (kt & 1) * 32 + (r >> 2) * 8 + (kt >> 1) * 4 + (r & 3);
        Roff[kt] = R * 64 + g0;
    }

    auto readK = [&](int b, bf16x8 (&ka)[4], bf16x8 (&kb)[4]) {
        const u16* base = &lk[b][0];
#pragma unroll
        for (int kt = 0; kt < 4; ++kt) {
            ka[kt] = *(const bf16x8*)&base[Roff[kt]];
            kb[kt] = *(const bf16x8*)&base[Roff[kt] ^ 32];
        }
    };

    stage(0, 0);
    stage(1, 64);
    __syncthreads(); // tiles 0,1 resident

    bf16x8 kaE[4], kbE[4], kaO[4], kbO[4]; // even/odd iter K-frag sets
    readK(0, kaE, kbE);

    int cur = 0, nx1 = 1, nx2 = 2;

    auto body = [&](int t, bf16x8 (&kaP)[4], bf16x8 (&kbP)[4],
                    bf16x8 (&kaN)[4], bf16x8 (&kbN)[4]) {
        if (t + 2 < 32) stage(nx2, (t + 2) * 64); // DMA flies under compute
        // V fragments for this tile (whole QK phase to land)
        bf16x8 vb[2][4];
#pragma unroll
        for (int h = 0; h < 2; ++h)
#pragma unroll
            for (int dt = 0; dt < 4; ++dt) {
                const int baseV = (dt * 2 + rhi) * 512 + rl * 64;
                vb[h][dt] = *(const bf16x8*)&lv[cur][baseV + ((h * 4 + quad) ^ rl) * 8];
            }
        // QK on PREFETCHED K-frags: starts immediately post-barrier
        bf16x4 pk4[2][4];
#pragma unroll
        for (int kt = 0; kt < 4; ++kt) {
#pragma unroll
            for (int qs = 0; qs < 2; ++qs) {
                f32x4 z = (f32x4){0.f, 0.f, 0.f, 0.f};
                __builtin_amdgcn_s_setprio(1);
                z = __builtin_amdgcn_mfma_f32_16x16x32_bf16(kaP[kt], qf[qs][0], z, 0, 0, 0);
                z = __builtin_amdgcn_mfma_f32_16x16x32_bf16(kbP[kt], qf[qs][1], z, 0, 0, 0);
                __builtin_amdgcn_s_setprio(0);
                bf16x4 pb;
                pb[0] = (__bf16)__builtin_amdgcn_exp2f(z[0]);
                pb[1] = (__bf16)__builtin_amdgcn_exp2f(z[1]);
                pb[2] = (__bf16)__builtin_amdgcn_exp2f(z[2]);
                pb[3] = (__bf16)__builtin_amdgcn_exp2f(z[3]);
                pk4[qs][kt] = pb;
            }
        }
        // prefetch NEXT iter's K-frags (tile t+1 drained at last barrier);
        // these reads overlap the PV MFMAs below and cross the barrier in regs
        if (t + 1 < 32) readK(nx1, kaN, kbN);
        // PV
        __builtin_amdgcn_s_setprio(1);
#pragma unroll
        for (int h = 0; h < 2; ++h) {
            const bf16x8 ap0 = __builtin_shufflevector(pk4[0][h], pk4[0][h + 2],
                                                       0, 1, 2, 3, 4, 5, 6, 7);
            const bf16x8 ap1 = __builtin_shufflevector(pk4[1][h], pk4[1][h + 2],
                                                       0, 1, 2, 3, 4, 5, 6, 7);
#pragma unroll
            for (int dt = 0; dt < 4; ++dt) {
                o[0][dt] = __builtin_amdgcn_mfma_f32_16x16x32_bf16(ap0, vb[h][dt],
                                                                  o[0][dt], 0, 0, 0);
                o[1][dt] = __builtin_amdgcn_mfma_f32_16x16x32_bf16(ap1, vb[h][dt],
                                                                  o[1][dt], 0, 0, 0);
            }
            osum[0] = __builtin_amdgcn_mfma_f32_16x16x32_bf16(ap0, vones, osum[0], 0, 0, 0);
            osum[1] = __builtin_amdgcn_mfma_f32_16x16x32_bf16(ap1, vones, osum[1], 0, 0, 0);
        }
        __builtin_amdgcn_s_setprio(0);

        __syncthreads(); // drains stage(t+2); tile t+1 already long-resident
        const int tmp = cur;
        cur = nx1;
        nx1 = nx2;
        nx2 = tmp;
    };

    for (int t = 0; t < 32; t += 2) {
        body(t, kaE, kbE, kaO, kbO);
        body(t + 1, kaO, kbO, kaE, kbE);
    }

    const int bb = bh >> 3, head = bh & 7;
#pragma unroll
    for (int qs = 0; qs < 2; ++qs) {
#pragma unroll
        for (int i = 0; i < 4; ++i) {
            const float inv = __builtin_amdgcn_rcpf(osum[qs][i]); // <=1 ulp, fine
            const int row = bb * 2048 + qt * 128 + w * 32 + qs * 16 + quad * 4 + i;
#pragma unroll
            for (int dt = 0; dt < 4; ++dt)
                attnb[(size_t)row * 512 + head * 64 + dt * 16 + r] =
                    f2bf(o[qs][dt][i] * inv);
        }
    }
}

// ---------------- launch ----------------
extern "C" void kernel_launch(void* const* d_in, const int* in_sizes, int n_in,
                              void* d_out, int out_size, void* d_ws, size_t ws_size,
                              hipStream_t stream) {
    const float *x = nullptr, *wq = nullptr, *bq = nullptr, *wp = nullptr, *bp = nullptr;
    for (int i = 0; i < n_in; ++i) {
        switch (in_sizes[i]) {
            case 4194304: x  = (const float*)d_in[i]; break;
            case 786432:  wq = (const float*)d_in[i]; break;
            case 1536:    bq = (const float*)d_in[i]; break;
            case 262144:  wp = (const float*)d_in[i]; break;
            case 512:     bp = (const float*)d_in[i]; break;
        }
    }
    if (!x || !wq || !bq || !wp || !bp) {
        x = (const float*)d_in[0]; wq = (const float*)d_in[1];
        bq = (const float*)d_in[2]; wp = (const float*)d_in[3];
        bp = (const float*)d_in[4];
    }
    float* out = (float*)d_out;

    // ws plan (32 MiB): attnb@0 (wqkvT aliases until attn), Qb@8M (wprojT
    // aliases after attn), Kb@16M, Vt@24M. xbf lives in d_out until proj.
    char* ws = (char*)d_ws;
    u16* attnb  = (u16*)(ws + 0);
    u16* wqkvT  = (u16*)(ws + 0);
    u16* Qb     = (u16*)(ws + 8388608);
    u16* wprojT = (u16*)(ws + 8388608);
    u16* Kb     = (u16*)(ws + 16777216);
    u16* Vt     = (u16*)(ws + 25165824);
    u16* xbf    = (u16*)d_out;

    prep_k<<<dim3(4288), 256, 0, stream>>>(x, xbf, wq, wqkvT);
    gemm_bt_k<0, 128><<<dim3(64, 12), 256, 0, stream>>>(xbf, wqkvT, bq, Qb, Kb, Vt,
                                                        nullptr);
    attn_k<<<dim3(16, 32), 256, 0, stream>>>(Qb, Kb, Vt, attnb);
    transpose_cvt_k<<<dim3(8, 8), dim3(64, 8), 0, stream>>>(wp, wprojT, 512, 512);
    gemm_bt_k<1, 64><<<dim3(64, 8), 256, 0, stream>>>(attnb, wprojT, bp, nullptr,
                                                      nullptr, nullptr, out);
}